// Round 1
// baseline (495.933 us; speedup 1.0000x reference)
//
#include <hip/hip_runtime.h>

typedef __bf16 bf16x8 __attribute__((ext_vector_type(8)));
typedef __bf16 bf16x4 __attribute__((ext_vector_type(4)));
typedef float  f32x4  __attribute__((ext_vector_type(4)));
typedef float  f32x2  __attribute__((ext_vector_type(2)));
typedef int    int4v  __attribute__((ext_vector_type(4)));

#define LL    384
#define CC    128
#define NROW  (LL * LL)   // 147456

#define MFMA16(a, b, c) __builtin_amdgcn_mfma_f32_16x16x32_bf16((a), (b), (c), 0, 0, 0)

__device__ __forceinline__ bf16x8 cvt8(const float* p) {
    f32x4 a = *reinterpret_cast<const f32x4*>(p);
    f32x4 b = *reinterpret_cast<const f32x4*>(p + 4);
    bf16x8 r;
    r[0] = (__bf16)a[0]; r[1] = (__bf16)a[1]; r[2] = (__bf16)a[2]; r[3] = (__bf16)a[3];
    r[4] = (__bf16)b[0]; r[5] = (__bf16)b[1]; r[6] = (__bf16)b[2]; r[7] = (__bf16)b[3];
    return r;
}
__device__ __forceinline__ bf16x8 ld_ws(const __bf16* p) {
    return __builtin_bit_cast(bf16x8, *reinterpret_cast<const int4v*>(p));
}
__device__ __forceinline__ float sigmf(float x) { return 1.f / (1.f + __expf(-x)); }

// ---------------------------------------------------------------------------
// Stage a 128x128 fp32 weight into LDS as bf16 MFMA fragments, lane-contiguous:
//   frag(ks,nt) for lane L lives at dst[((ks*8+nt)*64 + L)*8 .. +8]  (16 B)
//   element (c,k): nt=c>>4, n16=c&15, ks=k>>5, quad=(k>>3)&3, lane=quad*16+n16
// Reads are then conflict-free ds_read_b128 (wave reads 1 KB contiguous).
// ---------------------------------------------------------------------------
__device__ __forceinline__ void stage_weight(const float* __restrict__ w,
                                             __bf16* dst, int tid) {
    const int c   = tid >> 1;
    const int k0  = (tid & 1) * 64;
    const int nt  = c >> 4;
    const int n16 = c & 15;
    #pragma unroll
    for (int u = 0; u < 8; ++u) {
        const int k    = k0 + u * 8;
        const int ks   = k >> 5;
        const int quad = (k >> 3) & 3;
        bf16x8 v = cvt8(w + c * CC + k);
        *reinterpret_cast<int4v*>(dst + ((ks * 8 + nt) * 64 + quad * 16 + n16) * 8) =
            __builtin_bit_cast(int4v, v);
    }
}
__device__ __forceinline__ bf16x8 wfrag(const __bf16* base, int ks, int nt, int lane) {
    return ld_ws(base + ((ks * 8 + nt) * 64 + lane) * 8);
}

// ---------------------------------------------------------------------------
// k_proj: 128 rows/block (grid 1152). Two phases (left, right); each stages
// {gate_w, proj_w} as bf16 fragments in 64 KB LDS, then per wave (32 rows =
// 2 row-groups): gate GEMM -> sigmoid -> proj GEMM -> LN -> masked store to
// channel-major ws. x fragments live in registers across all 4 GEMMs.
// ---------------------------------------------------------------------------
__global__ __launch_bounds__(256, 2) void k_proj(
    const float* __restrict__ pf, const float* __restrict__ rmask,
    const float* __restrict__ lp_w, const float* __restrict__ lp_b,
    const float* __restrict__ lp_g, const float* __restrict__ lp_be,
    const float* __restrict__ rp_w, const float* __restrict__ rp_b,
    const float* __restrict__ rp_g, const float* __restrict__ rp_be,
    const float* __restrict__ lg_w, const float* __restrict__ lg_b,
    const float* __restrict__ rg_w, const float* __restrict__ rg_b,
    __bf16* __restrict__ pl_c, __bf16* __restrict__ pr_c)
{
    __shared__ __bf16 wl[2 * 16384];       // 65536 B

    const int tid  = threadIdx.x;
    const int wave = tid >> 6, lane = tid & 63;
    const int n16  = lane & 15, quad = lane >> 4;
    const int rowblock = blockIdx.x * 128 + wave * 32;

    // x fragments for 2 row-groups
    bf16x8 xf[2][4];
    #pragma unroll
    for (int rg = 0; rg < 2; ++rg) {
        const int r_a = rowblock + rg * 16 + n16;
        #pragma unroll
        for (int ks = 0; ks < 4; ++ks)
            xf[rg][ks] = cvt8(pf + (size_t)r_a * CC + ks * 32 + quad * 8);
    }

    // mask per row-group (D rows: rowblock + rg*16 + quad*4 + g)
    float mrow[2][4];
    #pragma unroll
    for (int rg = 0; rg < 2; ++rg) {
        const int rd   = rowblock + rg * 16 + quad * 4;
        const int i_id = rd / LL;
        const int k_id = rd - i_id * LL;      // rd%4==0 -> k_id+3 < 384
        float mi = rmask[i_id];
        #pragma unroll
        for (int g = 0; g < 4; ++g) mrow[rg][g] = mi * rmask[k_id + g];
    }

    auto phase = [&](const float* gw, const float* gb,
                     const float* pw, const float* pb,
                     const float* gamma, const float* beta,
                     __bf16* dst) {
        stage_weight(gw, wl, tid);
        stage_weight(pw, wl + 16384, tid);
        __syncthreads();

        f32x4 acc[2][8];
        // gate GEMM
        #pragma unroll
        for (int rg = 0; rg < 2; ++rg)
            #pragma unroll
            for (int nt = 0; nt < 8; ++nt) acc[rg][nt] = f32x4{0.f, 0.f, 0.f, 0.f};
        #pragma unroll
        for (int ks = 0; ks < 4; ++ks)
            #pragma unroll
            for (int nt = 0; nt < 8; ++nt) {
                bf16x8 wf = wfrag(wl, ks, nt, lane);
                #pragma unroll
                for (int rg = 0; rg < 2; ++rg)
                    acc[rg][nt] = MFMA16(xf[rg][ks], wf, acc[rg][nt]);
            }
        bf16x4 sg[2][8];
        #pragma unroll
        for (int rg = 0; rg < 2; ++rg)
            #pragma unroll
            for (int nt = 0; nt < 8; ++nt) {
                float bias = gb[nt * 16 + n16];
                #pragma unroll
                for (int g = 0; g < 4; ++g)
                    sg[rg][nt][g] = (__bf16)sigmf(acc[rg][nt][g] + bias);
            }
        // proj GEMM
        #pragma unroll
        for (int rg = 0; rg < 2; ++rg)
            #pragma unroll
            for (int nt = 0; nt < 8; ++nt) acc[rg][nt] = f32x4{0.f, 0.f, 0.f, 0.f};
        #pragma unroll
        for (int ks = 0; ks < 4; ++ks)
            #pragma unroll
            for (int nt = 0; nt < 8; ++nt) {
                bf16x8 wf = wfrag(wl + 16384, ks, nt, lane);
                #pragma unroll
                for (int rg = 0; rg < 2; ++rg)
                    acc[rg][nt] = MFMA16(xf[rg][ks], wf, acc[rg][nt]);
            }
        // bias + LN + combine + store
        #pragma unroll
        for (int rg = 0; rg < 2; ++rg) {
            #pragma unroll
            for (int nt = 0; nt < 8; ++nt) {
                float bias = pb[nt * 16 + n16];
                #pragma unroll
                for (int g = 0; g < 4; ++g) acc[rg][nt][g] += bias;
            }
            float s[4] = {0.f,0.f,0.f,0.f}, ss[4] = {0.f,0.f,0.f,0.f};
            #pragma unroll
            for (int nt = 0; nt < 8; ++nt)
                #pragma unroll
                for (int g = 0; g < 4; ++g) { float v = acc[rg][nt][g]; s[g] += v; ss[g] += v * v; }
            #pragma unroll
            for (int m = 1; m < 16; m <<= 1)
                #pragma unroll
                for (int g = 0; g < 4; ++g) {
                    s[g]  += __shfl_xor(s[g],  m, 64);
                    ss[g] += __shfl_xor(ss[g], m, 64);
                }
            float mean[4], rstd[4];
            #pragma unroll
            for (int g = 0; g < 4; ++g) {
                mean[g] = s[g] * (1.f / 128.f);
                float var = ss[g] * (1.f / 128.f) - mean[g] * mean[g];
                rstd[g] = rsqrtf(fmaxf(var, 0.f) + 1e-5f);
            }
            const int rd = rowblock + rg * 16 + quad * 4;
            #pragma unroll
            for (int nt = 0; nt < 8; ++nt) {
                const int c = nt * 16 + n16;
                float ga = gamma[c], be = beta[c];
                bf16x4 o;
                #pragma unroll
                for (int g = 0; g < 4; ++g) {
                    float v = (acc[rg][nt][g] - mean[g]) * rstd[g] * ga + be;
                    v *= mrow[rg][g] * (float)sg[rg][nt][g];
                    o[g] = (__bf16)v;
                }
                *reinterpret_cast<bf16x4*>(dst + (size_t)c * NROW + rd) = o;
            }
        }
        __syncthreads();   // protect wl before next phase restages
    };

    phase(lg_w, lg_b, lp_w, lp_b, lp_g, lp_be, pl_c);
    phase(rg_w, rg_b, rp_w, rp_b, rp_g, rp_be, pr_c);
}

// ---------------------------------------------------------------------------
// k_einsum v2: latency-bound fix. 1-D grid of 1152 blocks; block = 128i x 64j
// x 2 channels; 4 waves in 2x2, wave tile = 64i x 32j (4x2 frags x 2c).
//   acc = 2c*4t*2u*4 = 64 regs (vs 128 before) -> with __launch_bounds__(256,3)
//   the allocator must fit 170 total regs -> 3 waves/SIMD (was 2).
//   Per kt: 12 x 16B loads feed 16 MFMAs (0.75 KB/MFMA vs 1.25 before).
// Grid swizzle: id = r*144 + (q*18 + tile) keeps the 8 channel-pair blocks
// that share each 64B output line on one XCD (id%8 const) so 8B partial
// writes merge in that XCD's L2 instead of thrashing HBM.
// ---------------------------------------------------------------------------
__global__ __launch_bounds__(256, 3) void k_einsum(
    const __bf16* __restrict__ pl_c, const __bf16* __restrict__ pr_c,
    float* __restrict__ out)
{
    const int bid  = blockIdx.x;          // 0..1151
    const int r8   = bid / 144;           // 0..7  channel-sub-index
    const int base = bid - r8 * 144;      // 0..143
    const int q    = base / 18;           // 0..7  channel-group
    const int tile = base - q * 18;       // 0..17
    const int bx   = tile / 6;            // 0..2  (i)
    const int by   = tile - bx * 6;       // 0..5  (j)
    const int c0   = (q * 8 + r8) * 2;    // 0..126, even

    const int tid  = threadIdx.x;
    const int wave = tid >> 6, lane = tid & 63;
    const int n16  = lane & 15, quad = lane >> 4;
    const int i_w  = bx * 128 + (wave >> 1) * 64;
    const int j_w  = by * 64  + (wave & 1) * 32;

    const __bf16* P0 = pl_c + (size_t)c0 * NROW;
    const __bf16* P1 = P0 + NROW;
    const __bf16* Q0 = pr_c + (size_t)c0 * NROW;
    const __bf16* Q1 = Q0 + NROW;

    size_t off_i[4], off_j[2];
    #pragma unroll
    for (int t = 0; t < 4; ++t)
        off_i[t] = (size_t)(i_w + t * 16 + n16) * LL + quad * 8;
    #pragma unroll
    for (int u = 0; u < 2; ++u)
        off_j[u] = (size_t)(j_w + u * 16 + n16) * LL + quad * 8;

    f32x4 acc[2][4][2];
    #pragma unroll
    for (int t = 0; t < 4; ++t)
        #pragma unroll
        for (int u = 0; u < 2; ++u) {
            acc[0][t][u] = f32x4{0.f, 0.f, 0.f, 0.f};
            acc[1][t][u] = f32x4{0.f, 0.f, 0.f, 0.f};
        }

    #pragma unroll
    for (int kt = 0; kt < 12; ++kt) {
        const int ko = kt * 32;
        bf16x8 fj[2][2], fi[2][4];
        #pragma unroll
        for (int u = 0; u < 2; ++u) {
            fj[0][u] = ld_ws(Q0 + off_j[u] + ko);
            fj[1][u] = ld_ws(Q1 + off_j[u] + ko);
        }
        #pragma unroll
        for (int t = 0; t < 4; ++t) {
            fi[0][t] = ld_ws(P0 + off_i[t] + ko);
            fi[1][t] = ld_ws(P1 + off_i[t] + ko);
        }
        #pragma unroll
        for (int t = 0; t < 4; ++t)
            #pragma unroll
            for (int u = 0; u < 2; ++u) {
                acc[0][t][u] = MFMA16(fi[0][t], fj[0][u], acc[0][t][u]);  // D: m=i, n=j
                acc[1][t][u] = MFMA16(fi[1][t], fj[1][u], acc[1][t][u]);
            }
    }

    // store: thread owns (i = i_w + t*16 + quad*4 + g, j = j_w + u*16 + n16),
    // 2 consecutive channels -> 8B f32x2 store
    #pragma unroll
    for (int t = 0; t < 4; ++t)
        #pragma unroll
        for (int u = 0; u < 2; ++u)
            #pragma unroll
            for (int g = 0; g < 4; ++g) {
                const int i = i_w + t * 16 + quad * 4 + g;
                const int j = j_w + u * 16 + n16;
                f32x2 o;
                o[0] = acc[0][t][u][g];
                o[1] = acc[1][t][u][g];
                *reinterpret_cast<f32x2*>(out + ((size_t)i * LL + j) * CC + c0) = o;
            }
}

// ---------------------------------------------------------------------------
// k_final: 128 rows/block (grid 1152), in place on d_out:
//   out[r][:] = (LN(T[r]) @ ow^T + ob) * sigmoid(pf[r] @ og_w^T + og_b)
// ow/og_w staged once per block as bf16 fragments in 64 KB LDS.
// Row r is read and written only by its own threads; reads precede stores.
// ---------------------------------------------------------------------------
__global__ __launch_bounds__(256, 2) void k_final(
    float* out, const float* __restrict__ pf,
    const float* __restrict__ ol_g, const float* __restrict__ ol_be,
    const float* __restrict__ ow,   const float* __restrict__ ob,
    const float* __restrict__ og_w, const float* __restrict__ og_b)
{
    __shared__ __bf16 wl[2 * 16384];       // 65536 B
    const int tid  = threadIdx.x;
    const int wave = tid >> 6, lane = tid & 63;
    const int n16  = lane & 15, quad = lane >> 4;
    const int rowblock = blockIdx.x * 128 + wave * 32;

    stage_weight(ow,   wl,         tid);
    stage_weight(og_w, wl + 16384, tid);
    __syncthreads();

    #pragma unroll
    for (int rg = 0; rg < 2; ++rg) {
        const int r = rowblock + rg * 16 + n16;

        f32x4 tf[8];
        bf16x8 pff[4];
        #pragma unroll
        for (int ks = 0; ks < 4; ++ks) {
            const float* tp = out + (size_t)r * CC + ks * 32 + quad * 8;
            tf[2 * ks]     = *reinterpret_cast<const f32x4*>(tp);
            tf[2 * ks + 1] = *reinterpret_cast<const f32x4*>(tp + 4);
            pff[ks] = cvt8(pf + (size_t)r * CC + ks * 32 + quad * 8);
        }

        float s = 0.f, ss = 0.f;
        #pragma unroll
        for (int h = 0; h < 8; ++h)
            #pragma unroll
            for (int q = 0; q < 4; ++q) { float f = tf[h][q]; s += f; ss += f * f; }
        s += __shfl_xor(s, 16, 64);  ss += __shfl_xor(ss, 16, 64);
        s += __shfl_xor(s, 32, 64);  ss += __shfl_xor(ss, 32, 64);
        const float mean = s * (1.f / 128.f);
        const float rstd = rsqrtf(fmaxf(ss * (1.f / 128.f) - mean * mean, 0.f) + 1e-5f);

        bf16x8 xn[4];
        #pragma unroll
        for (int ks = 0; ks < 4; ++ks) {
            const int cb = ks * 32 + quad * 8;
            f32x4 g0 = *reinterpret_cast<const f32x4*>(ol_g + cb);
            f32x4 g1 = *reinterpret_cast<const f32x4*>(ol_g + cb + 4);
            f32x4 b0 = *reinterpret_cast<const f32x4*>(ol_be + cb);
            f32x4 b1 = *reinterpret_cast<const f32x4*>(ol_be + cb + 4);
            bf16x8 rv;
            #pragma unroll
            for (int q = 0; q < 4; ++q) {
                rv[q]     = (__bf16)((tf[2 * ks][q]     - mean) * rstd * g0[q] + b0[q]);
                rv[4 + q] = (__bf16)((tf[2 * ks + 1][q] - mean) * rstd * g1[q] + b1[q]);
            }
            xn[ks] = rv;
        }

        f32x4 ao[8], ag[8];
        #pragma unroll
        for (int mt = 0; mt < 8; ++mt) { ao[mt] = f32x4{0.f,0.f,0.f,0.f}; ag[mt] = f32x4{0.f,0.f,0.f,0.f}; }
        #pragma unroll
        for (int ks = 0; ks < 4; ++ks)
            #pragma unroll
            for (int mt = 0; mt < 8; ++mt) {
                bf16x8 awf = wfrag(wl,         ks, mt, lane);
                bf16x8 gwf = wfrag(wl + 16384, ks, mt, lane);
                ao[mt] = MFMA16(awf, xn[ks],  ao[mt]);   // m = c_out, n = row
                ag[mt] = MFMA16(gwf, pff[ks], ag[mt]);
            }

        #pragma unroll
        for (int mt = 0; mt < 8; ++mt) {
            const int c0 = mt * 16 + quad * 4;
            f32x4 bb = *reinterpret_cast<const f32x4*>(ob + c0);
            f32x4 gb = *reinterpret_cast<const f32x4*>(og_b + c0);
            f32x4 o;
            #pragma unroll
            for (int g = 0; g < 4; ++g) {
                float gate = sigmf(ag[mt][g] + gb[g]);
                o[g] = (ao[mt][g] + bb[g]) * gate;
            }
            *reinterpret_cast<f32x4*>(out + (size_t)r * CC + c0) = o;
        }
    }
}

// ---------------------------------------------------------------------------
extern "C" void kernel_launch(void* const* d_in, const int* in_sizes, int n_in,
                              void* d_out, int out_size, void* d_ws, size_t ws_size,
                              hipStream_t stream)
{
    const float* pf    = (const float*)d_in[0];
    const float* rmask = (const float*)d_in[1];
    const float* lp_w  = (const float*)d_in[2];
    const float* lp_b  = (const float*)d_in[3];
    const float* lp_g  = (const float*)d_in[4];
    const float* lp_be = (const float*)d_in[5];
    const float* rp_w  = (const float*)d_in[6];
    const float* rp_b  = (const float*)d_in[7];
    const float* rp_g  = (const float*)d_in[8];
    const float* rp_be = (const float*)d_in[9];
    const float* lg_w  = (const float*)d_in[10];
    const float* lg_b  = (const float*)d_in[11];
    const float* rg_w  = (const float*)d_in[12];
    const float* rg_b  = (const float*)d_in[13];
    const float* og_w  = (const float*)d_in[14];
    const float* og_b  = (const float*)d_in[15];
    const float* ol_g  = (const float*)d_in[16];
    const float* ol_be = (const float*)d_in[17];
    const float* ow    = (const float*)d_in[18];
    const float* ob    = (const float*)d_in[19];
    float* out = (float*)d_out;

    __bf16* pl_c = (__bf16*)d_ws;                 // [128][147456] bf16
    __bf16* pr_c = pl_c + (size_t)CC * NROW;      // [128][147456] bf16

    k_proj<<<NROW / 128, 256, 0, stream>>>(pf, rmask,
        lp_w, lp_b, lp_g, lp_be, rp_w, rp_b, rp_g, rp_be,
        lg_w, lg_b, rg_w, rg_b, pl_c, pr_c);
    k_einsum<<<1152, 256, 0, stream>>>(pl_c, pr_c, out);
    k_final<<<NROW / 128, 256, 0, stream>>>(out, pf,
        ol_g, ol_be, ow, ob, og_w, og_b);
}

// Round 2
// 353.023 us; speedup vs baseline: 1.4048x; 1.4048x over previous
//
#include <hip/hip_runtime.h>

typedef __bf16 bf16x8 __attribute__((ext_vector_type(8)));
typedef __bf16 bf16x4 __attribute__((ext_vector_type(4)));
typedef float  f32x4  __attribute__((ext_vector_type(4)));
typedef float  f32x2  __attribute__((ext_vector_type(2)));
typedef int    int4v  __attribute__((ext_vector_type(4)));

#define LL    384
#define CC    128
#define NROW  (LL * LL)   // 147456

#define MFMA16(a, b, c) __builtin_amdgcn_mfma_f32_16x16x32_bf16((a), (b), (c), 0, 0, 0)

__device__ __forceinline__ bf16x8 cvt8(const float* p) {
    f32x4 a = *reinterpret_cast<const f32x4*>(p);
    f32x4 b = *reinterpret_cast<const f32x4*>(p + 4);
    bf16x8 r;
    r[0] = (__bf16)a[0]; r[1] = (__bf16)a[1]; r[2] = (__bf16)a[2]; r[3] = (__bf16)a[3];
    r[4] = (__bf16)b[0]; r[5] = (__bf16)b[1]; r[6] = (__bf16)b[2]; r[7] = (__bf16)b[3];
    return r;
}
__device__ __forceinline__ bf16x8 ld_ws(const __bf16* p) {
    return __builtin_bit_cast(bf16x8, *reinterpret_cast<const int4v*>(p));
}
__device__ __forceinline__ float sigmf(float x) { return 1.f / (1.f + __expf(-x)); }

// async global->LDS, 16 B per lane; LDS dest is wave-uniform base + lane*16
__device__ __forceinline__ void gl16(const __bf16* g, __bf16* l) {
    __builtin_amdgcn_global_load_lds(
        (const __attribute__((address_space(1))) unsigned int*)g,
        (__attribute__((address_space(3))) unsigned int*)l,
        16, 0, 0);
}

// ---------------------------------------------------------------------------
// Stage a 128x128 fp32 weight into LDS as bf16 MFMA fragments, lane-contiguous:
//   frag(ks,nt) for lane L lives at dst[((ks*8+nt)*64 + L)*8 .. +8]  (16 B)
//   element (c,k): nt=c>>4, n16=c&15, ks=k>>5, quad=(k>>3)&3, lane=quad*16+n16
// Reads are then conflict-free ds_read_b128 (wave reads 1 KB contiguous).
// ---------------------------------------------------------------------------
__device__ __forceinline__ void stage_weight(const float* __restrict__ w,
                                             __bf16* dst, int tid) {
    const int c   = tid >> 1;
    const int k0  = (tid & 1) * 64;
    const int nt  = c >> 4;
    const int n16 = c & 15;
    #pragma unroll
    for (int u = 0; u < 8; ++u) {
        const int k    = k0 + u * 8;
        const int ks   = k >> 5;
        const int quad = (k >> 3) & 3;
        bf16x8 v = cvt8(w + c * CC + k);
        *reinterpret_cast<int4v*>(dst + ((ks * 8 + nt) * 64 + quad * 16 + n16) * 8) =
            __builtin_bit_cast(int4v, v);
    }
}
__device__ __forceinline__ bf16x8 wfrag(const __bf16* base, int ks, int nt, int lane) {
    return ld_ws(base + ((ks * 8 + nt) * 64 + lane) * 8);
}

// ---------------------------------------------------------------------------
// k_proj: 128 rows/block (grid 1152). Two phases (left, right); each stages
// {gate_w, proj_w} as bf16 fragments in 64 KB LDS, then per wave (32 rows =
// 2 row-groups): gate GEMM -> sigmoid -> proj GEMM -> LN -> masked store to
// channel-major ws. x fragments live in registers across all 4 GEMMs.
// ---------------------------------------------------------------------------
__global__ __launch_bounds__(256, 2) void k_proj(
    const float* __restrict__ pf, const float* __restrict__ rmask,
    const float* __restrict__ lp_w, const float* __restrict__ lp_b,
    const float* __restrict__ lp_g, const float* __restrict__ lp_be,
    const float* __restrict__ rp_w, const float* __restrict__ rp_b,
    const float* __restrict__ rp_g, const float* __restrict__ rp_be,
    const float* __restrict__ lg_w, const float* __restrict__ lg_b,
    const float* __restrict__ rg_w, const float* __restrict__ rg_b,
    __bf16* __restrict__ pl_c, __bf16* __restrict__ pr_c)
{
    __shared__ __bf16 wl[2 * 16384];       // 65536 B

    const int tid  = threadIdx.x;
    const int wave = tid >> 6, lane = tid & 63;
    const int n16  = lane & 15, quad = lane >> 4;
    const int rowblock = blockIdx.x * 128 + wave * 32;

    // x fragments for 2 row-groups
    bf16x8 xf[2][4];
    #pragma unroll
    for (int rg = 0; rg < 2; ++rg) {
        const int r_a = rowblock + rg * 16 + n16;
        #pragma unroll
        for (int ks = 0; ks < 4; ++ks)
            xf[rg][ks] = cvt8(pf + (size_t)r_a * CC + ks * 32 + quad * 8);
    }

    // mask per row-group (D rows: rowblock + rg*16 + quad*4 + g)
    float mrow[2][4];
    #pragma unroll
    for (int rg = 0; rg < 2; ++rg) {
        const int rd   = rowblock + rg * 16 + quad * 4;
        const int i_id = rd / LL;
        const int k_id = rd - i_id * LL;      // rd%4==0 -> k_id+3 < 384
        float mi = rmask[i_id];
        #pragma unroll
        for (int g = 0; g < 4; ++g) mrow[rg][g] = mi * rmask[k_id + g];
    }

    auto phase = [&](const float* gw, const float* gb,
                     const float* pw, const float* pb,
                     const float* gamma, const float* beta,
                     __bf16* dst) {
        stage_weight(gw, wl, tid);
        stage_weight(pw, wl + 16384, tid);
        __syncthreads();

        f32x4 acc[2][8];
        // gate GEMM
        #pragma unroll
        for (int rg = 0; rg < 2; ++rg)
            #pragma unroll
            for (int nt = 0; nt < 8; ++nt) acc[rg][nt] = f32x4{0.f, 0.f, 0.f, 0.f};
        #pragma unroll
        for (int ks = 0; ks < 4; ++ks)
            #pragma unroll
            for (int nt = 0; nt < 8; ++nt) {
                bf16x8 wf = wfrag(wl, ks, nt, lane);
                #pragma unroll
                for (int rg = 0; rg < 2; ++rg)
                    acc[rg][nt] = MFMA16(xf[rg][ks], wf, acc[rg][nt]);
            }
        bf16x4 sg[2][8];
        #pragma unroll
        for (int rg = 0; rg < 2; ++rg)
            #pragma unroll
            for (int nt = 0; nt < 8; ++nt) {
                float bias = gb[nt * 16 + n16];
                #pragma unroll
                for (int g = 0; g < 4; ++g)
                    sg[rg][nt][g] = (__bf16)sigmf(acc[rg][nt][g] + bias);
            }
        // proj GEMM
        #pragma unroll
        for (int rg = 0; rg < 2; ++rg)
            #pragma unroll
            for (int nt = 0; nt < 8; ++nt) acc[rg][nt] = f32x4{0.f, 0.f, 0.f, 0.f};
        #pragma unroll
        for (int ks = 0; ks < 4; ++ks)
            #pragma unroll
            for (int nt = 0; nt < 8; ++nt) {
                bf16x8 wf = wfrag(wl + 16384, ks, nt, lane);
                #pragma unroll
                for (int rg = 0; rg < 2; ++rg)
                    acc[rg][nt] = MFMA16(xf[rg][ks], wf, acc[rg][nt]);
            }
        // bias + LN + combine + store
        #pragma unroll
        for (int rg = 0; rg < 2; ++rg) {
            #pragma unroll
            for (int nt = 0; nt < 8; ++nt) {
                float bias = pb[nt * 16 + n16];
                #pragma unroll
                for (int g = 0; g < 4; ++g) acc[rg][nt][g] += bias;
            }
            float s[4] = {0.f,0.f,0.f,0.f}, ss[4] = {0.f,0.f,0.f,0.f};
            #pragma unroll
            for (int nt = 0; nt < 8; ++nt)
                #pragma unroll
                for (int g = 0; g < 4; ++g) { float v = acc[rg][nt][g]; s[g] += v; ss[g] += v * v; }
            #pragma unroll
            for (int m = 1; m < 16; m <<= 1)
                #pragma unroll
                for (int g = 0; g < 4; ++g) {
                    s[g]  += __shfl_xor(s[g],  m, 64);
                    ss[g] += __shfl_xor(ss[g], m, 64);
                }
            float mean[4], rstd[4];
            #pragma unroll
            for (int g = 0; g < 4; ++g) {
                mean[g] = s[g] * (1.f / 128.f);
                float var = ss[g] * (1.f / 128.f) - mean[g] * mean[g];
                rstd[g] = rsqrtf(fmaxf(var, 0.f) + 1e-5f);
            }
            const int rd = rowblock + rg * 16 + quad * 4;
            #pragma unroll
            for (int nt = 0; nt < 8; ++nt) {
                const int c = nt * 16 + n16;
                float ga = gamma[c], be = beta[c];
                bf16x4 o;
                #pragma unroll
                for (int g = 0; g < 4; ++g) {
                    float v = (acc[rg][nt][g] - mean[g]) * rstd[g] * ga + be;
                    v *= mrow[rg][g] * (float)sg[rg][nt][g];
                    o[g] = (__bf16)v;
                }
                *reinterpret_cast<bf16x4*>(dst + (size_t)c * NROW + rd) = o;
            }
        }
        __syncthreads();   // protect wl before next phase restages
    };

    phase(lg_w, lg_b, lp_w, lp_b, lp_g, lp_be, pl_c);
    phase(rg_w, rg_b, rp_w, rp_b, rp_g, rp_be, pr_c);
}

// ---------------------------------------------------------------------------
// k_einsum_tile: per-channel 128x128-tile GEMM, m97 structure.
//   grid 1152 = 128 channels x 9 tiles; XCD swizzle -> each XCD owns 16
//   whole channels (588 KB panels -> L2-resident, 3x reuse).
//   Block: 4 waves in 2x2; wave tile 64x64 (4x4 frags), acc = 64 VGPR.
//   K-loop: 12 steps of BK=32; LDS 2buf x (8KB A + 8KB B) = 32 KB staged by
//   global_load_lds DIRECTLY in fragment-major layout (slot s=mt*64+lane ->
//   row mt*16+n16, kchunk=quad) via per-lane pre-permuted global addresses;
//   ds_read_b128 then reads 1KB contiguous per wave (conflict-free).
//   Output T is channel-major f32 [c][i*384+j]: 16 n16-lanes store 64 B
//   contiguous -> full-line coalesced, no partial-line RMW (round-1 lesson).
// ---------------------------------------------------------------------------
__global__ __launch_bounds__(256, 3) void k_einsum_tile(
    const __bf16* __restrict__ pl_c, const __bf16* __restrict__ pr_c,
    float* __restrict__ T)
{
    __shared__ __bf16 sA[2][512 * 8];   // 8 KB per buffer
    __shared__ __bf16 sB[2][512 * 8];

    const int bid  = blockIdx.x;                    // 0..1151
    const int wgid = (bid & 7) * 144 + (bid >> 3);  // XCD-contiguous chunks
    const int ch   = wgid / 9;
    const int tile = wgid - ch * 9;
    const int i0   = (tile / 3) * 128;
    const int j0   = (tile % 3) * 128;

    const int tid  = threadIdx.x;
    const int w    = tid >> 6, lane = tid & 63;
    const int n16  = lane & 15, quad = lane >> 4;
    const int wr   = w >> 1, wc = w & 1;

    const __bf16* Pc = pl_c + (size_t)ch * NROW;
    const __bf16* Qc = pr_c + (size_t)ch * NROW;

    // staging source addrs at k0=0: instr u holds m-tile mt = w*2+u
    const __bf16* ga[2];
    const __bf16* gb[2];
    #pragma unroll
    for (int u = 0; u < 2; ++u) {
        const int row = (w * 2 + u) * 16 + n16;
        ga[u] = Pc + (size_t)(i0 + row) * LL + quad * 8;
        gb[u] = Qc + (size_t)(j0 + row) * LL + quad * 8;
    }

    f32x4 acc[4][4];
    #pragma unroll
    for (int m = 0; m < 4; ++m)
        #pragma unroll
        for (int n = 0; n < 4; ++n) acc[m][n] = f32x4{0.f, 0.f, 0.f, 0.f};

    auto STAGE = [&](int buf, int k0) {
        #pragma unroll
        for (int u = 0; u < 2; ++u) {
            __bf16* la = &sA[buf][(size_t)((w * 2 + u) * 64) * 8];
            __bf16* lb = &sB[buf][(size_t)((w * 2 + u) * 64) * 8];
            gl16(ga[u] + k0, la);
            gl16(gb[u] + k0, lb);
        }
    };

    STAGE(0, 0);
    __syncthreads();

    #pragma unroll
    for (int t = 0; t < 12; ++t) {
        if (t < 11) STAGE((t + 1) & 1, (t + 1) * 32);   // async prefetch
        const __bf16* Ab = sA[t & 1];
        const __bf16* Bb = sB[t & 1];
        bf16x8 af[4], bf[4];
        #pragma unroll
        for (int m = 0; m < 4; ++m) af[m] = ld_ws(Ab + ((size_t)((wr * 4 + m) * 64 + lane)) * 8);
        #pragma unroll
        for (int n = 0; n < 4; ++n) bf[n] = ld_ws(Bb + ((size_t)((wc * 4 + n) * 64 + lane)) * 8);
        #pragma unroll
        for (int m = 0; m < 4; ++m)
            #pragma unroll
            for (int n = 0; n < 4; ++n)
                acc[m][n] = MFMA16(af[m], bf[n], acc[m][n]);
        __syncthreads();   // drains prefetch (vmcnt) + protects read buffer
    }

    float* Tc = T + (size_t)ch * NROW;
    #pragma unroll
    for (int m = 0; m < 4; ++m) {
        const int i = i0 + wr * 64 + m * 16 + quad * 4;
        #pragma unroll
        for (int n = 0; n < 4; ++n) {
            const int j = j0 + wc * 64 + n * 16 + n16;
            #pragma unroll
            for (int g = 0; g < 4; ++g)
                Tc[(size_t)(i + g) * LL + j] = acc[m][n][g];
        }
    }
}

// ---------------------------------------------------------------------------
// k_final_cm: reads pre-LN T in CHANNEL-MAJOR layout (out-of-place), writes
// final output row-major to d_out.
//   out[r][:] = (LN(T[:,r]) @ ow^T + ob) * sigmoid(pf[r] @ og_w^T + og_b)
// T loads: lanes n16 = 16 consecutive rows -> each 4B-scalar load instr
// touches 4 full 64B lines (fully coalesced at line granularity).
// ---------------------------------------------------------------------------
__global__ __launch_bounds__(256, 2) void k_final_cm(
    float* __restrict__ out, const float* __restrict__ T,
    const float* __restrict__ pf,
    const float* __restrict__ ol_g, const float* __restrict__ ol_be,
    const float* __restrict__ ow,   const float* __restrict__ ob,
    const float* __restrict__ og_w, const float* __restrict__ og_b)
{
    __shared__ __bf16 wl[2 * 16384];       // 65536 B
    const int tid  = threadIdx.x;
    const int wave = tid >> 6, lane = tid & 63;
    const int n16  = lane & 15, quad = lane >> 4;
    const int rowblock = blockIdx.x * 128 + wave * 32;

    stage_weight(ow,   wl,         tid);
    stage_weight(og_w, wl + 16384, tid);
    __syncthreads();

    #pragma unroll
    for (int rg = 0; rg < 2; ++rg) {
        const int r = rowblock + rg * 16 + n16;

        f32x4 tf[8];
        bf16x8 pff[4];
        #pragma unroll
        for (int ks = 0; ks < 4; ++ks) {
            #pragma unroll
            for (int q = 0; q < 4; ++q) {
                tf[2 * ks][q]     = T[(size_t)(ks * 32 + quad * 8 + q)     * NROW + r];
                tf[2 * ks + 1][q] = T[(size_t)(ks * 32 + quad * 8 + 4 + q) * NROW + r];
            }
            pff[ks] = cvt8(pf + (size_t)r * CC + ks * 32 + quad * 8);
        }

        float s = 0.f, ss = 0.f;
        #pragma unroll
        for (int h = 0; h < 8; ++h)
            #pragma unroll
            for (int q = 0; q < 4; ++q) { float f = tf[h][q]; s += f; ss += f * f; }
        s += __shfl_xor(s, 16, 64);  ss += __shfl_xor(ss, 16, 64);
        s += __shfl_xor(s, 32, 64);  ss += __shfl_xor(ss, 32, 64);
        const float mean = s * (1.f / 128.f);
        const float rstd = rsqrtf(fmaxf(ss * (1.f / 128.f) - mean * mean, 0.f) + 1e-5f);

        bf16x8 xn[4];
        #pragma unroll
        for (int ks = 0; ks < 4; ++ks) {
            const int cb = ks * 32 + quad * 8;
            f32x4 g0 = *reinterpret_cast<const f32x4*>(ol_g + cb);
            f32x4 g1 = *reinterpret_cast<const f32x4*>(ol_g + cb + 4);
            f32x4 b0 = *reinterpret_cast<const f32x4*>(ol_be + cb);
            f32x4 b1 = *reinterpret_cast<const f32x4*>(ol_be + cb + 4);
            bf16x8 rv;
            #pragma unroll
            for (int q = 0; q < 4; ++q) {
                rv[q]     = (__bf16)((tf[2 * ks][q]     - mean) * rstd * g0[q] + b0[q]);
                rv[4 + q] = (__bf16)((tf[2 * ks + 1][q] - mean) * rstd * g1[q] + b1[q]);
            }
            xn[ks] = rv;
        }

        f32x4 ao[8], ag[8];
        #pragma unroll
        for (int mt = 0; mt < 8; ++mt) { ao[mt] = f32x4{0.f,0.f,0.f,0.f}; ag[mt] = f32x4{0.f,0.f,0.f,0.f}; }
        #pragma unroll
        for (int ks = 0; ks < 4; ++ks)
            #pragma unroll
            for (int mt = 0; mt < 8; ++mt) {
                bf16x8 awf = wfrag(wl,         ks, mt, lane);
                bf16x8 gwf = wfrag(wl + 16384, ks, mt, lane);
                ao[mt] = MFMA16(awf, xn[ks],  ao[mt]);   // m = c_out, n = row
                ag[mt] = MFMA16(gwf, pff[ks], ag[mt]);
            }

        #pragma unroll
        for (int mt = 0; mt < 8; ++mt) {
            const int c0 = mt * 16 + quad * 4;
            f32x4 bb = *reinterpret_cast<const f32x4*>(ob + c0);
            f32x4 gb = *reinterpret_cast<const f32x4*>(og_b + c0);
            f32x4 o;
            #pragma unroll
            for (int g = 0; g < 4; ++g) {
                float gate = sigmf(ag[mt][g] + gb[g]);
                o[g] = (ao[mt][g] + bb[g]) * gate;
            }
            *reinterpret_cast<f32x4*>(out + (size_t)r * CC + c0) = o;
        }
    }
}

// ---------------------------------------------------------------------------
// FALLBACK PATH (used only if ws_size cannot hold the channel-major T):
// round-0 proven kernels: direct-read einsum (writes row-major T into d_out)
// + in-place final.
// ---------------------------------------------------------------------------
__global__ __launch_bounds__(256, 2) void k_einsum_direct(
    const __bf16* __restrict__ pl_c, const __bf16* __restrict__ pr_c,
    float* __restrict__ out)
{
    const int tid  = threadIdx.x;
    const int wave = tid >> 6, lane = tid & 63;
    const int n16  = lane & 15, quad = lane >> 4;
    const int i0   = blockIdx.x * 64;
    const int jw   = blockIdx.y * 64 + wave * 16;
    const int c0   = blockIdx.z * 8;

    size_t off_i[4];
    #pragma unroll
    for (int t = 0; t < 4; ++t)
        off_i[t] = (size_t)(i0 + t * 16 + n16) * LL + quad * 8;
    const size_t off_j = (size_t)(jw + n16) * LL + quad * 8;

    f32x4 acc[8][4];
    #pragma unroll
    for (int c = 0; c < 8; ++c)
        #pragma unroll
        for (int t = 0; t < 4; ++t) acc[c][t] = f32x4{0.f, 0.f, 0.f, 0.f};

    #pragma unroll
    for (int c = 0; c < 8; ++c) {
        const __bf16* Pb = pl_c + (size_t)(c0 + c) * NROW;
        const __bf16* Qb = pr_c + (size_t)(c0 + c) * NROW + off_j;
        #pragma unroll
        for (int kt = 0; kt < 12; ++kt) {
            bf16x8 fj = ld_ws(Qb + kt * 32);
            #pragma unroll
            for (int t = 0; t < 4; ++t) {
                bf16x8 fi = ld_ws(Pb + off_i[t] + kt * 32);
                acc[c][t] = MFMA16(fi, fj, acc[c][t]);
            }
        }
    }

    #pragma unroll
    for (int t = 0; t < 4; ++t)
        #pragma unroll
        for (int g = 0; g < 4; ++g) {
            const int i = i0 + t * 16 + quad * 4 + g;
            float* dst = out + ((size_t)i * LL + jw + n16) * CC + c0;
            f32x4 lo, hi;
            #pragma unroll
            for (int q = 0; q < 4; ++q) { lo[q] = acc[q][t][g]; hi[q] = acc[4 + q][t][g]; }
            *reinterpret_cast<f32x4*>(dst)     = lo;
            *reinterpret_cast<f32x4*>(dst + 4) = hi;
        }
}

__global__ __launch_bounds__(256, 2) void k_final_ip(
    float* out, const float* __restrict__ pf,
    const float* __restrict__ ol_g, const float* __restrict__ ol_be,
    const float* __restrict__ ow,   const float* __restrict__ ob,
    const float* __restrict__ og_w, const float* __restrict__ og_b)
{
    __shared__ __bf16 wl[2 * 16384];
    const int tid  = threadIdx.x;
    const int wave = tid >> 6, lane = tid & 63;
    const int n16  = lane & 15, quad = lane >> 4;
    const int rowblock = blockIdx.x * 128 + wave * 32;

    stage_weight(ow,   wl,         tid);
    stage_weight(og_w, wl + 16384, tid);
    __syncthreads();

    #pragma unroll
    for (int rg = 0; rg < 2; ++rg) {
        const int r = rowblock + rg * 16 + n16;

        f32x4 tf[8];
        bf16x8 pff[4];
        #pragma unroll
        for (int ks = 0; ks < 4; ++ks) {
            const float* tp = out + (size_t)r * CC + ks * 32 + quad * 8;
            tf[2 * ks]     = *reinterpret_cast<const f32x4*>(tp);
            tf[2 * ks + 1] = *reinterpret_cast<const f32x4*>(tp + 4);
            pff[ks] = cvt8(pf + (size_t)r * CC + ks * 32 + quad * 8);
        }

        float s = 0.f, ss = 0.f;
        #pragma unroll
        for (int h = 0; h < 8; ++h)
            #pragma unroll
            for (int q = 0; q < 4; ++q) { float f = tf[h][q]; s += f; ss += f * f; }
        s += __shfl_xor(s, 16, 64);  ss += __shfl_xor(ss, 16, 64);
        s += __shfl_xor(s, 32, 64);  ss += __shfl_xor(ss, 32, 64);
        const float mean = s * (1.f / 128.f);
        const float rstd = rsqrtf(fmaxf(ss * (1.f / 128.f) - mean * mean, 0.f) + 1e-5f);

        bf16x8 xn[4];
        #pragma unroll
        for (int ks = 0; ks < 4; ++ks) {
            const int cb = ks * 32 + quad * 8;
            f32x4 g0 = *reinterpret_cast<const f32x4*>(ol_g + cb);
            f32x4 g1 = *reinterpret_cast<const f32x4*>(ol_g + cb + 4);
            f32x4 b0 = *reinterpret_cast<const f32x4*>(ol_be + cb);
            f32x4 b1 = *reinterpret_cast<const f32x4*>(ol_be + cb + 4);
            bf16x8 rv;
            #pragma unroll
            for (int q = 0; q < 4; ++q) {
                rv[q]     = (__bf16)((tf[2 * ks][q]     - mean) * rstd * g0[q] + b0[q]);
                rv[4 + q] = (__bf16)((tf[2 * ks + 1][q] - mean) * rstd * g1[q] + b1[q]);
            }
            xn[ks] = rv;
        }

        f32x4 ao[8], ag[8];
        #pragma unroll
        for (int mt = 0; mt < 8; ++mt) { ao[mt] = f32x4{0.f,0.f,0.f,0.f}; ag[mt] = f32x4{0.f,0.f,0.f,0.f}; }
        #pragma unroll
        for (int ks = 0; ks < 4; ++ks)
            #pragma unroll
            for (int mt = 0; mt < 8; ++mt) {
                bf16x8 awf = wfrag(wl,         ks, mt, lane);
                bf16x8 gwf = wfrag(wl + 16384, ks, mt, lane);
                ao[mt] = MFMA16(awf, xn[ks],  ao[mt]);
                ag[mt] = MFMA16(gwf, pff[ks], ag[mt]);
            }

        #pragma unroll
        for (int mt = 0; mt < 8; ++mt) {
            const int c0 = mt * 16 + quad * 4;
            f32x4 bb = *reinterpret_cast<const f32x4*>(ob + c0);
            f32x4 gb = *reinterpret_cast<const f32x4*>(og_b + c0);
            f32x4 o;
            #pragma unroll
            for (int g = 0; g < 4; ++g) {
                float gate = sigmf(ag[mt][g] + gb[g]);
                o[g] = (ao[mt][g] + bb[g]) * gate;
            }
            *reinterpret_cast<f32x4*>(out + (size_t)r * CC + c0) = o;
        }
    }
}

// ---------------------------------------------------------------------------
extern "C" void kernel_launch(void* const* d_in, const int* in_sizes, int n_in,
                              void* d_out, int out_size, void* d_ws, size_t ws_size,
                              hipStream_t stream)
{
    const float* pf    = (const float*)d_in[0];
    const float* rmask = (const float*)d_in[1];
    const float* lp_w  = (const float*)d_in[2];
    const float* lp_b  = (const float*)d_in[3];
    const float* lp_g  = (const float*)d_in[4];
    const float* lp_be = (const float*)d_in[5];
    const float* rp_w  = (const float*)d_in[6];
    const float* rp_b  = (const float*)d_in[7];
    const float* rp_g  = (const float*)d_in[8];
    const float* rp_be = (const float*)d_in[9];
    const float* lg_w  = (const float*)d_in[10];
    const float* lg_b  = (const float*)d_in[11];
    const float* rg_w  = (const float*)d_in[12];
    const float* rg_b  = (const float*)d_in[13];
    const float* og_w  = (const float*)d_in[14];
    const float* og_b  = (const float*)d_in[15];
    const float* ol_g  = (const float*)d_in[16];
    const float* ol_be = (const float*)d_in[17];
    const float* ow    = (const float*)d_in[18];
    const float* ob    = (const float*)d_in[19];
    float* out = (float*)d_out;

    __bf16* pl_c = (__bf16*)d_ws;                 // [128][147456] bf16
    __bf16* pr_c = pl_c + (size_t)CC * NROW;      // [128][147456] bf16
    float*  T    = (float*)(pr_c + (size_t)CC * NROW);  // [128][147456] f32

    const size_t need = (size_t)CC * NROW * (2 + 2 + 4);  // 151 MB

    k_proj<<<NROW / 128, 256, 0, stream>>>(pf, rmask,
        lp_w, lp_b, lp_g, lp_be, rp_w, rp_b, rp_g, rp_be,
        lg_w, lg_b, rg_w, rg_b, pl_c, pr_c);

    if (ws_size >= need) {
        k_einsum_tile<<<1152, 256, 0, stream>>>(pl_c, pr_c, T);
        k_final_cm<<<NROW / 128, 256, 0, stream>>>(out, T, pf,
            ol_g, ol_be, ow, ob, og_w, og_b);
    } else {
        k_einsum_direct<<<dim3(LL / 64, LL / 64, CC / 8), 256, 0, stream>>>(pl_c, pr_c, out);
        k_final_ip<<<NROW / 128, 256, 0, stream>>>(out, pf,
            ol_g, ol_be, ow, ob, og_w, og_b);
    }
}

// Round 3
// 312.747 us; speedup vs baseline: 1.5857x; 1.1288x over previous
//
#include <hip/hip_runtime.h>

typedef __bf16 bf16x8 __attribute__((ext_vector_type(8)));
typedef __bf16 bf16x4 __attribute__((ext_vector_type(4)));
typedef float  f32x4  __attribute__((ext_vector_type(4)));
typedef int    int4v  __attribute__((ext_vector_type(4)));

#define LL    384
#define CC    128
#define NROW  (LL * LL)   // 147456

#define MFMA16(a, b, c) __builtin_amdgcn_mfma_f32_16x16x32_bf16((a), (b), (c), 0, 0, 0)

__device__ __forceinline__ bf16x8 cvt8(const float* p) {
    f32x4 a = *reinterpret_cast<const f32x4*>(p);
    f32x4 b = *reinterpret_cast<const f32x4*>(p + 4);
    bf16x8 r;
    r[0] = (__bf16)a[0]; r[1] = (__bf16)a[1]; r[2] = (__bf16)a[2]; r[3] = (__bf16)a[3];
    r[4] = (__bf16)b[0]; r[5] = (__bf16)b[1]; r[6] = (__bf16)b[2]; r[7] = (__bf16)b[3];
    return r;
}
__device__ __forceinline__ bf16x8 ld_ws(const __bf16* p) {
    return __builtin_bit_cast(bf16x8, *reinterpret_cast<const int4v*>(p));
}
__device__ __forceinline__ float sigmf(float x) { return 1.f / (1.f + __expf(-x)); }

// async global->LDS, 16 B per lane; LDS dest is wave-uniform base + lane*16
__device__ __forceinline__ void gl16(const __bf16* g, __bf16* l) {
    __builtin_amdgcn_global_load_lds(
        (const __attribute__((address_space(1))) unsigned int*)g,
        (__attribute__((address_space(3))) unsigned int*)l,
        16, 0, 0);
}

// ---------------------------------------------------------------------------
// Fragment-major weight layout (what wfrag reads):
//   frag slot s = ks*8+nt, lane L = quad*16+n16, 8 bf16 (16 B) per (s,lane):
//     element (c,k): nt=c>>4, n16=c&15, ks=k>>5, quad=(k>>3)&3
//   linear: dst[(s*64 + L)*8 + e]
// stage_weight writes this layout from a [128][128] fp32 matrix (used by the
// one-shot k_wconv and the fallback kernels).
// ---------------------------------------------------------------------------
__device__ __forceinline__ void stage_weight(const float* __restrict__ w,
                                             __bf16* dst, int tid) {
    const int c   = tid >> 1;
    const int k0  = (tid & 1) * 64;
    const int nt  = c >> 4;
    const int n16 = c & 15;
    #pragma unroll
    for (int u = 0; u < 8; ++u) {
        const int k    = k0 + u * 8;
        const int ks   = k >> 5;
        const int quad = (k >> 3) & 3;
        bf16x8 v = cvt8(w + c * CC + k);
        *reinterpret_cast<int4v*>(dst + ((ks * 8 + nt) * 64 + quad * 16 + n16) * 8) =
            __builtin_bit_cast(int4v, v);
    }
}
__device__ __forceinline__ bf16x8 wfrag(const __bf16* base, int ks, int nt, int lane) {
    return ld_ws(base + ((ks * 8 + nt) * 64 + lane) * 8);
}

// one-shot: convert 6 weight matrices to fragment-major bf16 in workspace
__global__ __launch_bounds__(256) void k_wconv(
    const float* __restrict__ w0, const float* __restrict__ w1,
    const float* __restrict__ w2, const float* __restrict__ w3,
    const float* __restrict__ w4, const float* __restrict__ w5,
    __bf16* __restrict__ dst)
{
    const float* srcs[6] = {w0, w1, w2, w3, w4, w5};
    stage_weight(srcs[blockIdx.x], dst + (size_t)blockIdx.x * 16384, threadIdx.x);
}

// ---------------------------------------------------------------------------
// k_proj v3: 128 rows/block (grid 1152). Weights arrive pre-converted in
// fragment-major bf16 (wfm[0..3] = lg, lp, rg, rp); staging is 8 async
// global_load_lds (1 KB each) per wave per weight into a 2x32KB double
// buffer, issued BEFORE the GEMM that hides them and drained by the next
// __syncthreads. No cvt VALU, no LDS write conflicts, no staging stall.
// Per wave (32 rows): gate GEMM -> sigmoid -> proj GEMM -> LN -> masked
// store to channel-major ws. x fragments live in registers across all 4 GEMMs.
// ---------------------------------------------------------------------------
__global__ __launch_bounds__(256, 2) void k_proj(
    const float* __restrict__ pf, const float* __restrict__ rmask,
    const __bf16* __restrict__ wfm,
    const float* __restrict__ lp_b, const float* __restrict__ lp_g,
    const float* __restrict__ lp_be,
    const float* __restrict__ rp_b, const float* __restrict__ rp_g,
    const float* __restrict__ rp_be,
    const float* __restrict__ lg_b, const float* __restrict__ rg_b,
    __bf16* __restrict__ pl_c, __bf16* __restrict__ pr_c)
{
    __shared__ __bf16 wl[2][16384];        // 2 x 32 KB

    const int tid  = threadIdx.x;
    const int wave = tid >> 6, lane = tid & 63;
    const int n16  = lane & 15, quad = lane >> 4;
    const int rowblock = blockIdx.x * 128 + wave * 32;

    // async-stage one pre-converted weight (32 KB) into one LDS buffer
    auto STAGEW = [&](int widx, __bf16* dstL) {
        const __bf16* src = wfm + (size_t)widx * 16384;
        #pragma unroll
        for (int i = 0; i < 8; ++i) {
            const int s = wave * 8 + i;            // frag slot, 1 KB each
            gl16(src + (size_t)s * 512 + lane * 8, dstL + (size_t)s * 512);
        }
    };

    // x fragments for 2 row-groups
    bf16x8 xf[2][4];
    #pragma unroll
    for (int rg = 0; rg < 2; ++rg) {
        const int r_a = rowblock + rg * 16 + n16;
        #pragma unroll
        for (int ks = 0; ks < 4; ++ks)
            xf[rg][ks] = cvt8(pf + (size_t)r_a * CC + ks * 32 + quad * 8);
    }

    // mask per row-group (D rows: rowblock + rg*16 + quad*4 + g)
    float mrow[2][4];
    #pragma unroll
    for (int rg = 0; rg < 2; ++rg) {
        const int rd   = rowblock + rg * 16 + quad * 4;
        const int i_id = rd / LL;
        const int k_id = rd - i_id * LL;      // rd%4==0 -> k_id+3 < 384
        float mi = rmask[i_id];
        #pragma unroll
        for (int g = 0; g < 4; ++g) mrow[rg][g] = mi * rmask[k_id + g];
    }

    f32x4 acc[2][8];
    auto GEMM = [&](const __bf16* wb) {
        #pragma unroll
        for (int rg = 0; rg < 2; ++rg)
            #pragma unroll
            for (int nt = 0; nt < 8; ++nt) acc[rg][nt] = f32x4{0.f, 0.f, 0.f, 0.f};
        #pragma unroll
        for (int ks = 0; ks < 4; ++ks)
            #pragma unroll
            for (int nt = 0; nt < 8; ++nt) {
                bf16x8 wf = wfrag(wb, ks, nt, lane);
                #pragma unroll
                for (int rg = 0; rg < 2; ++rg)
                    acc[rg][nt] = MFMA16(xf[rg][ks], wf, acc[rg][nt]);
            }
    };

    bf16x4 sg[2][8];
    auto SIGM = [&](const float* gb) {
        #pragma unroll
        for (int rg = 0; rg < 2; ++rg)
            #pragma unroll
            for (int nt = 0; nt < 8; ++nt) {
                float bias = gb[nt * 16 + n16];
                #pragma unroll
                for (int g = 0; g < 4; ++g)
                    sg[rg][nt][g] = (__bf16)sigmf(acc[rg][nt][g] + bias);
            }
    };

    auto EPILOG = [&](const float* pb, const float* gamma, const float* beta,
                      __bf16* dst) {
        #pragma unroll
        for (int rg = 0; rg < 2; ++rg) {
            #pragma unroll
            for (int nt = 0; nt < 8; ++nt) {
                float bias = pb[nt * 16 + n16];
                #pragma unroll
                for (int g = 0; g < 4; ++g) acc[rg][nt][g] += bias;
            }
            float s[4] = {0.f,0.f,0.f,0.f}, ss[4] = {0.f,0.f,0.f,0.f};
            #pragma unroll
            for (int nt = 0; nt < 8; ++nt)
                #pragma unroll
                for (int g = 0; g < 4; ++g) { float v = acc[rg][nt][g]; s[g] += v; ss[g] += v * v; }
            #pragma unroll
            for (int m = 1; m < 16; m <<= 1)
                #pragma unroll
                for (int g = 0; g < 4; ++g) {
                    s[g]  += __shfl_xor(s[g],  m, 64);
                    ss[g] += __shfl_xor(ss[g], m, 64);
                }
            float mean[4], rstd[4];
            #pragma unroll
            for (int g = 0; g < 4; ++g) {
                mean[g] = s[g] * (1.f / 128.f);
                float var = ss[g] * (1.f / 128.f) - mean[g] * mean[g];
                rstd[g] = rsqrtf(fmaxf(var, 0.f) + 1e-5f);
            }
            const int rd = rowblock + rg * 16 + quad * 4;
            #pragma unroll
            for (int nt = 0; nt < 8; ++nt) {
                const int c = nt * 16 + n16;
                float ga = gamma[c], be = beta[c];
                bf16x4 o;
                #pragma unroll
                for (int g = 0; g < 4; ++g) {
                    float v = (acc[rg][nt][g] - mean[g]) * rstd[g] * ga + be;
                    v *= mrow[rg][g] * (float)sg[rg][nt][g];
                    o[g] = (__bf16)v;
                }
                *reinterpret_cast<bf16x4*>(dst + (size_t)c * NROW + rd) = o;
            }
        }
    };

    // pipeline: each prefetch is issued before the GEMM that hides it and
    // drained (vmcnt) by the following __syncthreads.
    STAGEW(0, wl[0]);                 // lg
    __syncthreads();

    STAGEW(1, wl[1]);                 // lp (lands during gate-L GEMM)
    GEMM(wl[0]);  SIGM(lg_b);
    __syncthreads();                  // lp ready; wl[0] reusable

    STAGEW(2, wl[0]);                 // rg (lands during proj-L GEMM)
    GEMM(wl[1]);  EPILOG(lp_b, lp_g, lp_be, pl_c);
    __syncthreads();                  // rg ready; wl[1] reusable

    STAGEW(3, wl[1]);                 // rp (lands during gate-R GEMM)
    GEMM(wl[0]);  SIGM(rg_b);
    __syncthreads();                  // rp ready

    GEMM(wl[1]);  EPILOG(rp_b, rp_g, rp_be, pr_c);
}

// ---------------------------------------------------------------------------
// k_einsum_tile: per-channel 128x128-tile GEMM, m97 structure (unchanged from
// round 2 -- it left the top-5).
// ---------------------------------------------------------------------------
__global__ __launch_bounds__(256, 3) void k_einsum_tile(
    const __bf16* __restrict__ pl_c, const __bf16* __restrict__ pr_c,
    float* __restrict__ T)
{
    __shared__ __bf16 sA[2][512 * 8];   // 8 KB per buffer
    __shared__ __bf16 sB[2][512 * 8];

    const int bid  = blockIdx.x;                    // 0..1151
    const int wgid = (bid & 7) * 144 + (bid >> 3);  // XCD-contiguous chunks
    const int ch   = wgid / 9;
    const int tile = wgid - ch * 9;
    const int i0   = (tile / 3) * 128;
    const int j0   = (tile % 3) * 128;

    const int tid  = threadIdx.x;
    const int w    = tid >> 6, lane = tid & 63;
    const int n16  = lane & 15, quad = lane >> 4;
    const int wr   = w >> 1, wc = w & 1;

    const __bf16* Pc = pl_c + (size_t)ch * NROW;
    const __bf16* Qc = pr_c + (size_t)ch * NROW;

    const __bf16* ga[2];
    const __bf16* gb[2];
    #pragma unroll
    for (int u = 0; u < 2; ++u) {
        const int row = (w * 2 + u) * 16 + n16;
        ga[u] = Pc + (size_t)(i0 + row) * LL + quad * 8;
        gb[u] = Qc + (size_t)(j0 + row) * LL + quad * 8;
    }

    f32x4 acc[4][4];
    #pragma unroll
    for (int m = 0; m < 4; ++m)
        #pragma unroll
        for (int n = 0; n < 4; ++n) acc[m][n] = f32x4{0.f, 0.f, 0.f, 0.f};

    auto STAGE = [&](int buf, int k0) {
        #pragma unroll
        for (int u = 0; u < 2; ++u) {
            __bf16* la = &sA[buf][(size_t)((w * 2 + u) * 64) * 8];
            __bf16* lb = &sB[buf][(size_t)((w * 2 + u) * 64) * 8];
            gl16(ga[u] + k0, la);
            gl16(gb[u] + k0, lb);
        }
    };

    STAGE(0, 0);
    __syncthreads();

    #pragma unroll
    for (int t = 0; t < 12; ++t) {
        if (t < 11) STAGE((t + 1) & 1, (t + 1) * 32);   // async prefetch
        const __bf16* Ab = sA[t & 1];
        const __bf16* Bb = sB[t & 1];
        bf16x8 af[4], bf[4];
        #pragma unroll
        for (int m = 0; m < 4; ++m) af[m] = ld_ws(Ab + ((size_t)((wr * 4 + m) * 64 + lane)) * 8);
        #pragma unroll
        for (int n = 0; n < 4; ++n) bf[n] = ld_ws(Bb + ((size_t)((wc * 4 + n) * 64 + lane)) * 8);
        #pragma unroll
        for (int m = 0; m < 4; ++m)
            #pragma unroll
            for (int n = 0; n < 4; ++n)
                acc[m][n] = MFMA16(af[m], bf[n], acc[m][n]);
        __syncthreads();   // drains prefetch (vmcnt) + protects read buffer
    }

    float* Tc = T + (size_t)ch * NROW;
    #pragma unroll
    for (int m = 0; m < 4; ++m) {
        const int i = i0 + wr * 64 + m * 16 + quad * 4;
        #pragma unroll
        for (int n = 0; n < 4; ++n) {
            const int j = j0 + wc * 64 + n * 16 + n16;
            #pragma unroll
            for (int g = 0; g < 4; ++g)
                Tc[(size_t)(i + g) * LL + j] = acc[m][n][g];
        }
    }
}

// ---------------------------------------------------------------------------
// k_final_cm v2: pre-converted ow/og fragments staged via async gl16 (one
// sync); reads pre-LN T channel-major, writes final output row-major.
// ---------------------------------------------------------------------------
__global__ __launch_bounds__(256, 2) void k_final_cm(
    float* __restrict__ out, const float* __restrict__ T,
    const float* __restrict__ pf, const __bf16* __restrict__ wfm,
    const float* __restrict__ ol_g, const float* __restrict__ ol_be,
    const float* __restrict__ ob,   const float* __restrict__ og_b)
{
    __shared__ __bf16 wl[2][16384];        // 2 x 32 KB: ow, og
    const int tid  = threadIdx.x;
    const int wave = tid >> 6, lane = tid & 63;
    const int n16  = lane & 15, quad = lane >> 4;
    const int rowblock = blockIdx.x * 128 + wave * 32;

    #pragma unroll
    for (int i = 0; i < 8; ++i) {
        const int s = wave * 8 + i;
        gl16(wfm + (size_t)(4 * 16384) + (size_t)s * 512 + lane * 8, wl[0] + (size_t)s * 512);
        gl16(wfm + (size_t)(5 * 16384) + (size_t)s * 512 + lane * 8, wl[1] + (size_t)s * 512);
    }
    __syncthreads();

    #pragma unroll
    for (int rg = 0; rg < 2; ++rg) {
        const int r = rowblock + rg * 16 + n16;

        f32x4 tf[8];
        bf16x8 pff[4];
        #pragma unroll
        for (int ks = 0; ks < 4; ++ks) {
            #pragma unroll
            for (int q = 0; q < 4; ++q) {
                tf[2 * ks][q]     = T[(size_t)(ks * 32 + quad * 8 + q)     * NROW + r];
                tf[2 * ks + 1][q] = T[(size_t)(ks * 32 + quad * 8 + 4 + q) * NROW + r];
            }
            pff[ks] = cvt8(pf + (size_t)r * CC + ks * 32 + quad * 8);
        }

        float s = 0.f, ss = 0.f;
        #pragma unroll
        for (int h = 0; h < 8; ++h)
            #pragma unroll
            for (int q = 0; q < 4; ++q) { float f = tf[h][q]; s += f; ss += f * f; }
        s += __shfl_xor(s, 16, 64);  ss += __shfl_xor(ss, 16, 64);
        s += __shfl_xor(s, 32, 64);  ss += __shfl_xor(ss, 32, 64);
        const float mean = s * (1.f / 128.f);
        const float rstd = rsqrtf(fmaxf(ss * (1.f / 128.f) - mean * mean, 0.f) + 1e-5f);

        bf16x8 xn[4];
        #pragma unroll
        for (int ks = 0; ks < 4; ++ks) {
            const int cb = ks * 32 + quad * 8;
            f32x4 g0 = *reinterpret_cast<const f32x4*>(ol_g + cb);
            f32x4 g1 = *reinterpret_cast<const f32x4*>(ol_g + cb + 4);
            f32x4 b0 = *reinterpret_cast<const f32x4*>(ol_be + cb);
            f32x4 b1 = *reinterpret_cast<const f32x4*>(ol_be + cb + 4);
            bf16x8 rv;
            #pragma unroll
            for (int q = 0; q < 4; ++q) {
                rv[q]     = (__bf16)((tf[2 * ks][q]     - mean) * rstd * g0[q] + b0[q]);
                rv[4 + q] = (__bf16)((tf[2 * ks + 1][q] - mean) * rstd * g1[q] + b1[q]);
            }
            xn[ks] = rv;
        }

        f32x4 ao[8], ag[8];
        #pragma unroll
        for (int mt = 0; mt < 8; ++mt) { ao[mt] = f32x4{0.f,0.f,0.f,0.f}; ag[mt] = f32x4{0.f,0.f,0.f,0.f}; }
        #pragma unroll
        for (int ks = 0; ks < 4; ++ks)
            #pragma unroll
            for (int mt = 0; mt < 8; ++mt) {
                bf16x8 awf = wfrag(wl[0], ks, mt, lane);
                bf16x8 gwf = wfrag(wl[1], ks, mt, lane);
                ao[mt] = MFMA16(awf, xn[ks],  ao[mt]);   // m = c_out, n = row
                ag[mt] = MFMA16(gwf, pff[ks], ag[mt]);
            }

        #pragma unroll
        for (int mt = 0; mt < 8; ++mt) {
            const int c0 = mt * 16 + quad * 4;
            f32x4 bb = *reinterpret_cast<const f32x4*>(ob + c0);
            f32x4 gb = *reinterpret_cast<const f32x4*>(og_b + c0);
            f32x4 o;
            #pragma unroll
            for (int g = 0; g < 4; ++g) {
                float gate = sigmf(ag[mt][g] + gb[g]);
                o[g] = (ao[mt][g] + bb[g]) * gate;
            }
            *reinterpret_cast<f32x4*>(out + (size_t)r * CC + c0) = o;
        }
    }
}

// ---------------------------------------------------------------------------
// FALLBACK PATH (used only if ws_size cannot hold the channel-major T):
// round-0 proven kernels operating from raw fp32 weights.
// ---------------------------------------------------------------------------
__global__ __launch_bounds__(256, 2) void k_proj_fb(
    const float* __restrict__ pf, const float* __restrict__ rmask,
    const float* __restrict__ lp_w, const float* __restrict__ lp_b,
    const float* __restrict__ lp_g, const float* __restrict__ lp_be,
    const float* __restrict__ rp_w, const float* __restrict__ rp_b,
    const float* __restrict__ rp_g, const float* __restrict__ rp_be,
    const float* __restrict__ lg_w, const float* __restrict__ lg_b,
    const float* __restrict__ rg_w, const float* __restrict__ rg_b,
    __bf16* __restrict__ pl_c, __bf16* __restrict__ pr_c)
{
    __shared__ __bf16 wl[2 * 16384];

    const int tid  = threadIdx.x;
    const int wave = tid >> 6, lane = tid & 63;
    const int n16  = lane & 15, quad = lane >> 4;
    const int rowblock = blockIdx.x * 128 + wave * 32;

    bf16x8 xf[2][4];
    #pragma unroll
    for (int rg = 0; rg < 2; ++rg) {
        const int r_a = rowblock + rg * 16 + n16;
        #pragma unroll
        for (int ks = 0; ks < 4; ++ks)
            xf[rg][ks] = cvt8(pf + (size_t)r_a * CC + ks * 32 + quad * 8);
    }

    float mrow[2][4];
    #pragma unroll
    for (int rg = 0; rg < 2; ++rg) {
        const int rd   = rowblock + rg * 16 + quad * 4;
        const int i_id = rd / LL;
        const int k_id = rd - i_id * LL;
        float mi = rmask[i_id];
        #pragma unroll
        for (int g = 0; g < 4; ++g) mrow[rg][g] = mi * rmask[k_id + g];
    }

    auto phase = [&](const float* gw, const float* gb,
                     const float* pw, const float* pb,
                     const float* gamma, const float* beta,
                     __bf16* dst) {
        stage_weight(gw, wl, tid);
        stage_weight(pw, wl + 16384, tid);
        __syncthreads();

        f32x4 acc[2][8];
        #pragma unroll
        for (int rg = 0; rg < 2; ++rg)
            #pragma unroll
            for (int nt = 0; nt < 8; ++nt) acc[rg][nt] = f32x4{0.f, 0.f, 0.f, 0.f};
        #pragma unroll
        for (int ks = 0; ks < 4; ++ks)
            #pragma unroll
            for (int nt = 0; nt < 8; ++nt) {
                bf16x8 wf = wfrag(wl, ks, nt, lane);
                #pragma unroll
                for (int rg = 0; rg < 2; ++rg)
                    acc[rg][nt] = MFMA16(xf[rg][ks], wf, acc[rg][nt]);
            }
        bf16x4 sg[2][8];
        #pragma unroll
        for (int rg = 0; rg < 2; ++rg)
            #pragma unroll
            for (int nt = 0; nt < 8; ++nt) {
                float bias = gb[nt * 16 + n16];
                #pragma unroll
                for (int g = 0; g < 4; ++g)
                    sg[rg][nt][g] = (__bf16)sigmf(acc[rg][nt][g] + bias);
            }
        #pragma unroll
        for (int rg = 0; rg < 2; ++rg)
            #pragma unroll
            for (int nt = 0; nt < 8; ++nt) acc[rg][nt] = f32x4{0.f, 0.f, 0.f, 0.f};
        #pragma unroll
        for (int ks = 0; ks < 4; ++ks)
            #pragma unroll
            for (int nt = 0; nt < 8; ++nt) {
                bf16x8 wf = wfrag(wl + 16384, ks, nt, lane);
                #pragma unroll
                for (int rg = 0; rg < 2; ++rg)
                    acc[rg][nt] = MFMA16(xf[rg][ks], wf, acc[rg][nt]);
            }
        #pragma unroll
        for (int rg = 0; rg < 2; ++rg) {
            #pragma unroll
            for (int nt = 0; nt < 8; ++nt) {
                float bias = pb[nt * 16 + n16];
                #pragma unroll
                for (int g = 0; g < 4; ++g) acc[rg][nt][g] += bias;
            }
            float s[4] = {0.f,0.f,0.f,0.f}, ss[4] = {0.f,0.f,0.f,0.f};
            #pragma unroll
            for (int nt = 0; nt < 8; ++nt)
                #pragma unroll
                for (int g = 0; g < 4; ++g) { float v = acc[rg][nt][g]; s[g] += v; ss[g] += v * v; }
            #pragma unroll
            for (int m = 1; m < 16; m <<= 1)
                #pragma unroll
                for (int g = 0; g < 4; ++g) {
                    s[g]  += __shfl_xor(s[g],  m, 64);
                    ss[g] += __shfl_xor(ss[g], m, 64);
                }
            float mean[4], rstd[4];
            #pragma unroll
            for (int g = 0; g < 4; ++g) {
                mean[g] = s[g] * (1.f / 128.f);
                float var = ss[g] * (1.f / 128.f) - mean[g] * mean[g];
                rstd[g] = rsqrtf(fmaxf(var, 0.f) + 1e-5f);
            }
            const int rd = rowblock + rg * 16 + quad * 4;
            #pragma unroll
            for (int nt = 0; nt < 8; ++nt) {
                const int c = nt * 16 + n16;
                float ga = gamma[c], be = beta[c];
                bf16x4 o;
                #pragma unroll
                for (int g = 0; g < 4; ++g) {
                    float v = (acc[rg][nt][g] - mean[g]) * rstd[g] * ga + be;
                    v *= mrow[rg][g] * (float)sg[rg][nt][g];
                    o[g] = (__bf16)v;
                }
                *reinterpret_cast<bf16x4*>(dst + (size_t)c * NROW + rd) = o;
            }
        }
        __syncthreads();
    };

    phase(lg_w, lg_b, lp_w, lp_b, lp_g, lp_be, pl_c);
    phase(rg_w, rg_b, rp_w, rp_b, rp_g, rp_be, pr_c);
}

__global__ __launch_bounds__(256, 2) void k_einsum_direct(
    const __bf16* __restrict__ pl_c, const __bf16* __restrict__ pr_c,
    float* __restrict__ out)
{
    const int tid  = threadIdx.x;
    const int wave = tid >> 6, lane = tid & 63;
    const int n16  = lane & 15, quad = lane >> 4;
    const int i0   = blockIdx.x * 64;
    const int jw   = blockIdx.y * 64 + wave * 16;
    const int c0   = blockIdx.z * 8;

    size_t off_i[4];
    #pragma unroll
    for (int t = 0; t < 4; ++t)
        off_i[t] = (size_t)(i0 + t * 16 + n16) * LL + quad * 8;
    const size_t off_j = (size_t)(jw + n16) * LL + quad * 8;

    f32x4 acc[8][4];
    #pragma unroll
    for (int c = 0; c < 8; ++c)
        #pragma unroll
        for (int t = 0; t < 4; ++t) acc[c][t] = f32x4{0.f, 0.f, 0.f, 0.f};

    #pragma unroll
    for (int c = 0; c < 8; ++c) {
        const __bf16* Pb = pl_c + (size_t)(c0 + c) * NROW;
        const __bf16* Qb = pr_c + (size_t)(c0 + c) * NROW + off_j;
        #pragma unroll
        for (int kt = 0; kt < 12; ++kt) {
            bf16x8 fj = ld_ws(Qb + kt * 32);
            #pragma unroll
            for (int t = 0; t < 4; ++t) {
                bf16x8 fi = ld_ws(Pb + off_i[t] + kt * 32);
                acc[c][t] = MFMA16(fi, fj, acc[c][t]);
            }
        }
    }

    #pragma unroll
    for (int t = 0; t < 4; ++t)
        #pragma unroll
        for (int g = 0; g < 4; ++g) {
            const int i = i0 + t * 16 + quad * 4 + g;
            float* dst = out + ((size_t)i * LL + jw + n16) * CC + c0;
            f32x4 lo, hi;
            #pragma unroll
            for (int q = 0; q < 4; ++q) { lo[q] = acc[q][t][g]; hi[q] = acc[4 + q][t][g]; }
            *reinterpret_cast<f32x4*>(dst)     = lo;
            *reinterpret_cast<f32x4*>(dst + 4) = hi;
        }
}

__global__ __launch_bounds__(256, 2) void k_final_ip(
    float* out, const float* __restrict__ pf,
    const float* __restrict__ ol_g, const float* __restrict__ ol_be,
    const float* __restrict__ ow,   const float* __restrict__ ob,
    const float* __restrict__ og_w, const float* __restrict__ og_b)
{
    __shared__ __bf16 wl[2 * 16384];
    const int tid  = threadIdx.x;
    const int wave = tid >> 6, lane = tid & 63;
    const int n16  = lane & 15, quad = lane >> 4;
    const int rowblock = blockIdx.x * 128 + wave * 32;

    stage_weight(ow,   wl,         tid);
    stage_weight(og_w, wl + 16384, tid);
    __syncthreads();

    #pragma unroll
    for (int rg = 0; rg < 2; ++rg) {
        const int r = rowblock + rg * 16 + n16;

        f32x4 tf[8];
        bf16x8 pff[4];
        #pragma unroll
        for (int ks = 0; ks < 4; ++ks) {
            const float* tp = out + (size_t)r * CC + ks * 32 + quad * 8;
            tf[2 * ks]     = *reinterpret_cast<const f32x4*>(tp);
            tf[2 * ks + 1] = *reinterpret_cast<const f32x4*>(tp + 4);
            pff[ks] = cvt8(pf + (size_t)r * CC + ks * 32 + quad * 8);
        }

        float s = 0.f, ss = 0.f;
        #pragma unroll
        for (int h = 0; h < 8; ++h)
            #pragma unroll
            for (int q = 0; q < 4; ++q) { float f = tf[h][q]; s += f; ss += f * f; }
        s += __shfl_xor(s, 16, 64);  ss += __shfl_xor(ss, 16, 64);
        s += __shfl_xor(s, 32, 64);  ss += __shfl_xor(ss, 32, 64);
        const float mean = s * (1.f / 128.f);
        const float rstd = rsqrtf(fmaxf(ss * (1.f / 128.f) - mean * mean, 0.f) + 1e-5f);

        bf16x8 xn[4];
        #pragma unroll
        for (int ks = 0; ks < 4; ++ks) {
            const int cb = ks * 32 + quad * 8;
            f32x4 g0 = *reinterpret_cast<const f32x4*>(ol_g + cb);
            f32x4 g1 = *reinterpret_cast<const f32x4*>(ol_g + cb + 4);
            f32x4 b0 = *reinterpret_cast<const f32x4*>(ol_be + cb);
            f32x4 b1 = *reinterpret_cast<const f32x4*>(ol_be + cb + 4);
            bf16x8 rv;
            #pragma unroll
            for (int q = 0; q < 4; ++q) {
                rv[q]     = (__bf16)((tf[2 * ks][q]     - mean) * rstd * g0[q] + b0[q]);
                rv[4 + q] = (__bf16)((tf[2 * ks + 1][q] - mean) * rstd * g1[q] + b1[q]);
            }
            xn[ks] = rv;
        }

        f32x4 ao[8], ag[8];
        #pragma unroll
        for (int mt = 0; mt < 8; ++mt) { ao[mt] = f32x4{0.f,0.f,0.f,0.f}; ag[mt] = f32x4{0.f,0.f,0.f,0.f}; }
        #pragma unroll
        for (int ks = 0; ks < 4; ++ks)
            #pragma unroll
            for (int mt = 0; mt < 8; ++mt) {
                bf16x8 awf = wfrag(wl,         ks, mt, lane);
                bf16x8 gwf = wfrag(wl + 16384, ks, mt, lane);
                ao[mt] = MFMA16(awf, xn[ks],  ao[mt]);
                ag[mt] = MFMA16(gwf, pff[ks], ag[mt]);
            }

        #pragma unroll
        for (int mt = 0; mt < 8; ++mt) {
            const int c0 = mt * 16 + quad * 4;
            f32x4 bb = *reinterpret_cast<const f32x4*>(ob + c0);
            f32x4 gb = *reinterpret_cast<const f32x4*>(og_b + c0);
            f32x4 o;
            #pragma unroll
            for (int g = 0; g < 4; ++g) {
                float gate = sigmf(ag[mt][g] + gb[g]);
                o[g] = (ao[mt][g] + bb[g]) * gate;
            }
            *reinterpret_cast<f32x4*>(out + (size_t)r * CC + c0) = o;
        }
    }
}

// ---------------------------------------------------------------------------
extern "C" void kernel_launch(void* const* d_in, const int* in_sizes, int n_in,
                              void* d_out, int out_size, void* d_ws, size_t ws_size,
                              hipStream_t stream)
{
    const float* pf    = (const float*)d_in[0];
    const float* rmask = (const float*)d_in[1];
    const float* lp_w  = (const float*)d_in[2];
    const float* lp_b  = (const float*)d_in[3];
    const float* lp_g  = (const float*)d_in[4];
    const float* lp_be = (const float*)d_in[5];
    const float* rp_w  = (const float*)d_in[6];
    const float* rp_b  = (const float*)d_in[7];
    const float* rp_g  = (const float*)d_in[8];
    const float* rp_be = (const float*)d_in[9];
    const float* lg_w  = (const float*)d_in[10];
    const float* lg_b  = (const float*)d_in[11];
    const float* rg_w  = (const float*)d_in[12];
    const float* rg_b  = (const float*)d_in[13];
    const float* og_w  = (const float*)d_in[14];
    const float* og_b  = (const float*)d_in[15];
    const float* ol_g  = (const float*)d_in[16];
    const float* ol_be = (const float*)d_in[17];
    const float* ow    = (const float*)d_in[18];
    const float* ob    = (const float*)d_in[19];
    float* out = (float*)d_out;

    __bf16* pl_c = (__bf16*)d_ws;                       // [128][147456] bf16
    __bf16* pr_c = pl_c + (size_t)CC * NROW;            // [128][147456] bf16
    __bf16* wfm  = pr_c + (size_t)CC * NROW;            // [6][16384] bf16 frag-major
    float*  T    = (float*)(wfm + 6 * 16384);           // [128][147456] f32

    const size_t need = (size_t)CC * NROW * (2 + 2 + 4) + 6 * 16384 * 2;

    if (ws_size >= need) {
        k_wconv<<<6, 256, 0, stream>>>(lg_w, lp_w, rg_w, rp_w, ow, og_w, wfm);
        k_proj<<<NROW / 128, 256, 0, stream>>>(pf, rmask, wfm,
            lp_b, lp_g, lp_be, rp_b, rp_g, rp_be, lg_b, rg_b, pl_c, pr_c);
        k_einsum_tile<<<1152, 256, 0, stream>>>(pl_c, pr_c, T);
        k_final_cm<<<NROW / 128, 256, 0, stream>>>(out, T, pf, wfm,
            ol_g, ol_be, ob, og_b);
    } else {
        k_proj_fb<<<NROW / 128, 256, 0, stream>>>(pf, rmask,
            lp_w, lp_b, lp_g, lp_be, rp_w, rp_b, rp_g, rp_be,
            lg_w, lg_b, rg_w, rg_b, pl_c, pr_c);
        k_einsum_direct<<<dim3(LL / 64, LL / 64, CC / 8), 256, 0, stream>>>(pl_c, pr_c, out);
        k_final_ip<<<NROW / 128, 256, 0, stream>>>(out, pf,
            ol_g, ol_be, ow, ob, og_w, og_b);
    }
}